// Round 4
// baseline (286.284 us; speedup 1.0000x reference)
//
#include <hip/hip_runtime.h>
#include <math.h>

#define NC 722
#define NROWS 65536
#define PAIRS_PER_WAVE 4
#define ROWS_PER_WAVE 8              // 4 aligned row-pairs
#define WAVES_PER_BLOCK 4
#define ROWS_PER_BLOCK 32
#define NF4 361                      // float4 per row-pair (2*722*4B / 16B)

__global__ void init_out_kernel(float* out) {
    if (threadIdx.x == 0) out[0] = 0.0f;
}

__global__ __launch_bounds__(256) void ce_gauss_kernel(
        const float* __restrict__ pred,
        const int* __restrict__ target,
        float* __restrict__ out) {
    const int lane = threadIdx.x & 63;
    const int wave = threadIdx.x >> 6;

    __shared__ float wt_lds[WAVES_PER_BLOCK][ROWS_PER_WAVE * 8]; // [0..6]=w, [7]=sumw
    __shared__ float se_lds[WAVES_PER_BLOCK][ROWS_PER_WAVE];
    __shared__ int   tg_lds[WAVES_PER_BLOCK][ROWS_PER_WAVE];
    __shared__ float wave_sums[WAVES_PER_BLOCK];

    const int row0 = blockIdx.x * ROWS_PER_BLOCK + wave * ROWS_PER_WAVE;

    // ---- main pass first: 4 row-pairs, float4 loads, sum-of-exp ----
    // Row pair p covers rows (row0+2p, row0+2p+1); base is 16B-aligned because
    // row0 is a multiple of 8 and 2 rows = 5776 B = 361 float4 exactly.
    const float4* __restrict__ p4[PAIRS_PER_WAVE];
    #pragma unroll
    for (int p = 0; p < PAIRS_PER_WAVE; ++p)
        p4[p] = (const float4*)(pred + (size_t)(row0 + 2 * p) * NC);

    float se[ROWS_PER_WAVE] = {0.f, 0.f, 0.f, 0.f, 0.f, 0.f, 0.f, 0.f};
    #pragma unroll
    for (int k = 0; k < 6; ++k) {
        const int g = lane + (k << 6);
        if (g < NF4) {
            const bool aE = (g < 180);   // all 4 elements in even row
            const bool aO = (g > 180);   // all 4 elements in odd row
            // g==180 straddles: x,y -> even row (elems 720,721), z,w -> odd (0,1)
            #pragma unroll
            for (int p = 0; p < PAIRS_PER_WAVE; ++p) {
                float4 v = p4[p][g];
                float e0 = __expf(v.x), e1 = __expf(v.y);
                float e2 = __expf(v.z), e3 = __expf(v.w);
                float s01 = e0 + e1, s23 = e2 + e3, s4 = s01 + s23;
                se[2 * p]     += aE ? s4 : (aO ? 0.f : s01);
                se[2 * p + 1] += aO ? s4 : (aE ? 0.f : s23);
            }
        }
    }

    // ---- weight-table sim (wave-uniform; runs in the load-latency shadow) ----
    // DECAYS[d] = exp(-(2^d)/4): d=1 -> 0.6065, 2 -> 0.3679, 3 -> 0.1353
    {
        const float DEC1 = 0.606530659713f;
        const float DEC2 = 0.367879441171f;
        const float DEC3 = 0.135335283237f;
        #pragma unroll
        for (int rr = 0; rr < ROWS_PER_WAVE; ++rr) {
            const int t = target[row0 + rr];   // uniform -> s_load
            float w[7] = {0.f, 0.f, 0.f, 0.f, 0.f, 0.f, 0.f};
            // Replay reference scatter: dist = 3..1, +1 then -1; later
            // (smaller-dist) writes overwrite, incl. clamped collisions.
            #pragma unroll
            for (int dist = 3; dist >= 1; --dist) {
                const float dv = (dist == 3) ? DEC3 : (dist == 2) ? DEC2 : DEC1;
                int ip = t + dist; if (ip > NC - 1) ip = NC - 1;
                int im = t - dist; if (im < 0) im = 0;
                w[ip - t + 3] = dv;
                w[im - t + 3] = dv;
            }
            w[3] = 1.0f;  // dist-0 write then exact-target set -> 1.0
            const float sw = w[0] + w[1] + w[2] + w[3] + w[4] + w[5] + w[6];
            if (lane == 0) {
                #pragma unroll
                for (int j = 0; j < 7; ++j) wt_lds[wave][rr * 8 + j] = w[j];
                wt_lds[wave][rr * 8 + 7] = sw;
                tg_lds[wave][rr] = t;
            }
        }
    }

    // ---- butterfly-reduce each row's sum-of-exp across the wave ----
    #pragma unroll
    for (int rr = 0; rr < ROWS_PER_WAVE; ++rr) {
        #pragma unroll
        for (int off = 32; off > 0; off >>= 1)
            se[rr] += __shfl_xor(se[rr], off, 64);
    }
    if (lane == 0) {
        #pragma unroll
        for (int rr = 0; rr < ROWS_PER_WAVE; ++rr) se_lds[wave][rr] = se[rr];
    }

    // ---- parallel 7-tap dot: lane = 8*rr + j handles row rr, tap j ----
    const int grr = lane >> 3;   // row within wave (0..7)
    const int gj  = lane & 7;    // tap (0..7; 7 inactive)
    const int t   = tg_lds[wave][grr];
    float dotv = 0.f;
    if (gj < 7) {
        const float wv = wt_lds[wave][grr * 8 + gj];
        if (wv > 0.f) {  // zero weight also masks out-of-range classes
            dotv = wv * pred[(size_t)(row0 + grr) * NC + (t - 3 + gj)];  // L1-hot
        }
    }
    dotv += __shfl_xor(dotv, 1, 64);
    dotv += __shfl_xor(dotv, 2, 64);
    dotv += __shfl_xor(dotv, 4, 64);

    // ---- per-row loss on lane 8*rr, then wave + block reduction ----
    float acc = 0.f;
    if (gj == 0) {
        const float sw  = wt_lds[wave][grr * 8 + 7];
        const float sev = se_lds[wave][grr];
        acc = sw * __logf(sev) - dotv;
    }
    #pragma unroll
    for (int off = 32; off > 0; off >>= 1)
        acc += __shfl_xor(acc, off, 64);

    if (lane == 0) wave_sums[wave] = acc;
    __syncthreads();
    if (threadIdx.x == 0) {
        float s = wave_sums[0] + wave_sums[1] + wave_sums[2] + wave_sums[3];
        atomicAdd(out, s * (1.0f / (float)NROWS));
    }
}

extern "C" void kernel_launch(void* const* d_in, const int* in_sizes, int n_in,
                              void* d_out, int out_size, void* d_ws, size_t ws_size,
                              hipStream_t stream) {
    const float* pred = (const float*)d_in[0];
    const int* target = (const int*)d_in[1];
    float* out = (float*)d_out;

    init_out_kernel<<<1, 64, 0, stream>>>(out);

    const int grid = NROWS / ROWS_PER_BLOCK;  // 2048 blocks
    ce_gauss_kernel<<<grid, 256, 0, stream>>>(pred, target, out);
}

// Round 5
// 261.532 us; speedup vs baseline: 1.0946x; 1.0946x over previous
//
#include <hip/hip_runtime.h>
#include <math.h>

#define NC 722
#define NF2 361            // float2 per row (722/2); rows 8B-aligned
#define NROWS 65536
#define ROWS_PER_WAVE 4
#define WAVES_PER_BLOCK 4
#define ROWS_PER_BLOCK 16
#define KITERS 6           // ceil(361/64)

__global__ void init_out_kernel(float* out) {
    if (threadIdx.x == 0) out[0] = 0.0f;
}

__global__ __launch_bounds__(256) void ce_gauss_kernel(
        const float* __restrict__ pred,
        const int* __restrict__ target,
        float* __restrict__ out) {
    const int lane = threadIdx.x & 63;
    const int wave = threadIdx.x >> 6;

    __shared__ float wt_lds[WAVES_PER_BLOCK][ROWS_PER_WAVE * 8]; // [0..6]=w, [7]=sumw
    __shared__ float se_lds[WAVES_PER_BLOCK][ROWS_PER_WAVE];
    __shared__ int   tg_lds[WAVES_PER_BLOCK][ROWS_PER_WAVE];
    __shared__ float wave_sums[WAVES_PER_BLOCK];

    const int row0 = blockIdx.x * ROWS_PER_BLOCK + wave * ROWS_PER_WAVE;

    // ---- phase 1: issue ALL loads unconditionally (clamped tail addr) ----
    const float2* __restrict__ p2[ROWS_PER_WAVE];
    #pragma unroll
    for (int rr = 0; rr < ROWS_PER_WAVE; ++rr)
        p2[rr] = (const float2*)(pred + (size_t)(row0 + rr) * NC);

    float2 v[ROWS_PER_WAVE][KITERS];
    #pragma unroll
    for (int k = 0; k < KITERS; ++k) {
        int idx = lane + (k << 6);
        if (idx > NF2 - 1) idx = NF2 - 1;   // clamp; only k=5, lane>40
        #pragma unroll
        for (int rr = 0; rr < ROWS_PER_WAVE; ++rr)
            v[rr][k] = p2[rr][idx];
    }

    // ---- weight-table sim in the load-latency shadow (wave-uniform) ----
    // DECAYS[d] = exp(-(2^d)/4): d=1 -> 0.6065, 2 -> 0.3679, 3 -> 0.1353
    {
        const float DEC1 = 0.606530659713f;
        const float DEC2 = 0.367879441171f;
        const float DEC3 = 0.135335283237f;
        #pragma unroll
        for (int rr = 0; rr < ROWS_PER_WAVE; ++rr) {
            const int t = target[row0 + rr];   // uniform -> s_load
            float w[7] = {0.f, 0.f, 0.f, 0.f, 0.f, 0.f, 0.f};
            // Replay reference scatter: dist = 3..1, +1 then -1; later
            // (smaller-dist) writes overwrite, incl. clamped collisions.
            #pragma unroll
            for (int dist = 3; dist >= 1; --dist) {
                const float dv = (dist == 3) ? DEC3 : (dist == 2) ? DEC2 : DEC1;
                int ip = t + dist; if (ip > NC - 1) ip = NC - 1;
                int im = t - dist; if (im < 0) im = 0;
                w[ip - t + 3] = dv;
                w[im - t + 3] = dv;
            }
            w[3] = 1.0f;  // dist-0 write then exact-target set -> 1.0
            const float sw = w[0] + w[1] + w[2] + w[3] + w[4] + w[5] + w[6];
            if (lane == 0) {
                #pragma unroll
                for (int j = 0; j < 7; ++j) wt_lds[wave][rr * 8 + j] = w[j];
                wt_lds[wave][rr * 8 + 7] = sw;
                tg_lds[wave][rr] = t;
            }
        }
    }

    // ---- phase 2: exp + accumulate (tail lanes masked to 0) ----
    float se[ROWS_PER_WAVE] = {0.f, 0.f, 0.f, 0.f};
    #pragma unroll
    for (int k = 0; k < KITERS; ++k) {
        const bool valid = (k < KITERS - 1) || (lane < NF2 - 5 * 64); // lane<41
        #pragma unroll
        for (int rr = 0; rr < ROWS_PER_WAVE; ++rr) {
            const float s = __expf(v[rr][k].x) + __expf(v[rr][k].y);
            se[rr] += valid ? s : 0.f;
        }
    }

    // ---- butterfly-reduce each row's sum-of-exp across the wave ----
    #pragma unroll
    for (int rr = 0; rr < ROWS_PER_WAVE; ++rr) {
        #pragma unroll
        for (int off = 32; off > 0; off >>= 1)
            se[rr] += __shfl_xor(se[rr], off, 64);
    }
    if (lane == 0) {
        #pragma unroll
        for (int rr = 0; rr < ROWS_PER_WAVE; ++rr) se_lds[wave][rr] = se[rr];
    }

    // ---- parallel 7-tap dot: lane = 8*rr + j handles row rr, tap j ----
    const int grr = lane >> 3;   // row slot (0..7; only 0..3 used)
    const int gj  = lane & 7;    // tap (0..7; 7 inactive)
    float dotv = 0.f;
    if (grr < ROWS_PER_WAVE && gj < 7) {
        const int t = tg_lds[wave][grr];
        const float wv = wt_lds[wave][grr * 8 + gj];
        if (wv > 0.f) {  // zero weight also masks out-of-range classes
            dotv = wv * pred[(size_t)(row0 + grr) * NC + (t - 3 + gj)];  // cache-hot
        }
    }
    dotv += __shfl_xor(dotv, 1, 64);
    dotv += __shfl_xor(dotv, 2, 64);
    dotv += __shfl_xor(dotv, 4, 64);

    // ---- per-row loss on lane 8*rr, then wave + block reduction ----
    float acc = 0.f;
    if (gj == 0 && grr < ROWS_PER_WAVE) {
        const float sw  = wt_lds[wave][grr * 8 + 7];
        const float sev = se_lds[wave][grr];
        acc = sw * __logf(sev) - dotv;
    }
    #pragma unroll
    for (int off = 32; off > 0; off >>= 1)
        acc += __shfl_xor(acc, off, 64);

    if (lane == 0) wave_sums[wave] = acc;
    __syncthreads();
    if (threadIdx.x == 0) {
        float s = wave_sums[0] + wave_sums[1] + wave_sums[2] + wave_sums[3];
        atomicAdd(out, s * (1.0f / (float)NROWS));
    }
}

extern "C" void kernel_launch(void* const* d_in, const int* in_sizes, int n_in,
                              void* d_out, int out_size, void* d_ws, size_t ws_size,
                              hipStream_t stream) {
    const float* pred = (const float*)d_in[0];
    const int* target = (const int*)d_in[1];
    float* out = (float*)d_out;

    init_out_kernel<<<1, 64, 0, stream>>>(out);

    const int grid = NROWS / ROWS_PER_BLOCK;  // 4096 blocks
    ce_gauss_kernel<<<grid, 256, 0, stream>>>(pred, target, out);
}

// Round 6
// 257.949 us; speedup vs baseline: 1.1098x; 1.0139x over previous
//
#include <hip/hip_runtime.h>
#include <math.h>

#define NC 722
#define NF2 361            // float2 per row (722/2); rows 8B-aligned
#define NROWS 65536
#define ROWS_PER_WAVE 4
#define WAVES_PER_BLOCK 4
#define ROWS_PER_BLOCK 16
#define KITERS 6           // ceil(361/64)
#define NBLOCKS (NROWS / ROWS_PER_BLOCK)   // 4096

__global__ __launch_bounds__(256) void ce_gauss_kernel(
        const float* __restrict__ pred,
        const int* __restrict__ target,
        float* __restrict__ partials) {
    const int lane = threadIdx.x & 63;
    const int wave = threadIdx.x >> 6;

    __shared__ float wt_lds[WAVES_PER_BLOCK][ROWS_PER_WAVE * 8]; // [0..6]=w, [7]=sumw
    __shared__ float se_lds[WAVES_PER_BLOCK][ROWS_PER_WAVE];
    __shared__ int   tg_lds[WAVES_PER_BLOCK][ROWS_PER_WAVE];
    __shared__ float wave_sums[WAVES_PER_BLOCK];

    const int row0 = blockIdx.x * ROWS_PER_BLOCK + wave * ROWS_PER_WAVE;

    // ---- phase 1: issue ALL loads unconditionally (clamped tail addr) ----
    const float2* __restrict__ p2[ROWS_PER_WAVE];
    #pragma unroll
    for (int rr = 0; rr < ROWS_PER_WAVE; ++rr)
        p2[rr] = (const float2*)(pred + (size_t)(row0 + rr) * NC);

    float2 v[ROWS_PER_WAVE][KITERS];
    #pragma unroll
    for (int k = 0; k < KITERS; ++k) {
        int idx = lane + (k << 6);
        if (idx > NF2 - 1) idx = NF2 - 1;   // clamp; only k=5, lane>40
        #pragma unroll
        for (int rr = 0; rr < ROWS_PER_WAVE; ++rr)
            v[rr][k] = p2[rr][idx];
    }

    // ---- weight-table sim in the load-latency shadow (wave-uniform) ----
    // DECAYS[d] = exp(-(2^d)/4): d=1 -> 0.6065, 2 -> 0.3679, 3 -> 0.1353
    {
        const float DEC1 = 0.606530659713f;
        const float DEC2 = 0.367879441171f;
        const float DEC3 = 0.135335283237f;
        #pragma unroll
        for (int rr = 0; rr < ROWS_PER_WAVE; ++rr) {
            const int t = target[row0 + rr];   // uniform -> s_load
            float w[7] = {0.f, 0.f, 0.f, 0.f, 0.f, 0.f, 0.f};
            // Replay reference scatter: dist = 3..1, +1 then -1; later
            // (smaller-dist) writes overwrite, incl. clamped collisions.
            #pragma unroll
            for (int dist = 3; dist >= 1; --dist) {
                const float dv = (dist == 3) ? DEC3 : (dist == 2) ? DEC2 : DEC1;
                int ip = t + dist; if (ip > NC - 1) ip = NC - 1;
                int im = t - dist; if (im < 0) im = 0;
                w[ip - t + 3] = dv;
                w[im - t + 3] = dv;
            }
            w[3] = 1.0f;  // dist-0 write then exact-target set -> 1.0
            const float sw = w[0] + w[1] + w[2] + w[3] + w[4] + w[5] + w[6];
            if (lane == 0) {
                #pragma unroll
                for (int j = 0; j < 7; ++j) wt_lds[wave][rr * 8 + j] = w[j];
                wt_lds[wave][rr * 8 + 7] = sw;
                tg_lds[wave][rr] = t;
            }
        }
    }

    // ---- phase 2: exp + accumulate (tail lanes masked to 0) ----
    float se[ROWS_PER_WAVE] = {0.f, 0.f, 0.f, 0.f};
    #pragma unroll
    for (int k = 0; k < KITERS; ++k) {
        const bool valid = (k < KITERS - 1) || (lane < NF2 - 5 * 64); // lane<41
        #pragma unroll
        for (int rr = 0; rr < ROWS_PER_WAVE; ++rr) {
            const float s = __expf(v[rr][k].x) + __expf(v[rr][k].y);
            se[rr] += valid ? s : 0.f;
        }
    }

    // ---- butterfly-reduce each row's sum-of-exp across the wave ----
    #pragma unroll
    for (int rr = 0; rr < ROWS_PER_WAVE; ++rr) {
        #pragma unroll
        for (int off = 32; off > 0; off >>= 1)
            se[rr] += __shfl_xor(se[rr], off, 64);
    }
    if (lane == 0) {
        #pragma unroll
        for (int rr = 0; rr < ROWS_PER_WAVE; ++rr) se_lds[wave][rr] = se[rr];
    }

    // ---- parallel 7-tap dot: lane = 8*rr + j handles row rr, tap j ----
    const int grr = lane >> 3;   // row slot (0..7; only 0..3 used)
    const int gj  = lane & 7;    // tap (0..7; 7 inactive)
    float dotv = 0.f;
    if (grr < ROWS_PER_WAVE && gj < 7) {
        const int t = tg_lds[wave][grr];
        const float wv = wt_lds[wave][grr * 8 + gj];
        if (wv > 0.f) {  // zero weight also masks out-of-range classes
            dotv = wv * pred[(size_t)(row0 + grr) * NC + (t - 3 + gj)];  // cache-hot
        }
    }
    dotv += __shfl_xor(dotv, 1, 64);
    dotv += __shfl_xor(dotv, 2, 64);
    dotv += __shfl_xor(dotv, 4, 64);

    // ---- per-row loss on lane 8*rr, then wave + block reduction ----
    float acc = 0.f;
    if (gj == 0 && grr < ROWS_PER_WAVE) {
        const float sw  = wt_lds[wave][grr * 8 + 7];
        const float sev = se_lds[wave][grr];
        acc = sw * __logf(sev) - dotv;
    }
    #pragma unroll
    for (int off = 32; off > 0; off >>= 1)
        acc += __shfl_xor(acc, off, 64);

    if (lane == 0) wave_sums[wave] = acc;
    __syncthreads();
    // Contention-free: one plain store per block (was: same-address atomicAdd
    // across 4096 blocks -> serialized at one L2 slice, ~60+ us tail).
    if (threadIdx.x == 0) {
        partials[blockIdx.x] =
            wave_sums[0] + wave_sums[1] + wave_sums[2] + wave_sums[3];
    }
}

__global__ __launch_bounds__(256) void reduce_partials_kernel(
        const float* __restrict__ partials, float* __restrict__ out) {
    const int lane = threadIdx.x & 63;
    const int wave = threadIdx.x >> 6;
    __shared__ float ws[4];

    float s = 0.f;
    #pragma unroll
    for (int k = 0; k < NBLOCKS / 256; ++k)          // 16 coalesced iters
        s += partials[threadIdx.x + (k << 8)];
    #pragma unroll
    for (int off = 32; off > 0; off >>= 1)
        s += __shfl_xor(s, off, 64);
    if (lane == 0) ws[wave] = s;
    __syncthreads();
    if (threadIdx.x == 0)
        out[0] = (ws[0] + ws[1] + ws[2] + ws[3]) * (1.0f / (float)NROWS);
}

extern "C" void kernel_launch(void* const* d_in, const int* in_sizes, int n_in,
                              void* d_out, int out_size, void* d_ws, size_t ws_size,
                              hipStream_t stream) {
    const float* pred = (const float*)d_in[0];
    const int* target = (const int*)d_in[1];
    float* out = (float*)d_out;
    float* partials = (float*)d_ws;   // 4096 floats = 16 KB

    ce_gauss_kernel<<<NBLOCKS, 256, 0, stream>>>(pred, target, partials);
    reduce_partials_kernel<<<1, 256, 0, stream>>>(partials, out);
}

// Round 7
// 254.377 us; speedup vs baseline: 1.1254x; 1.0140x over previous
//
#include <hip/hip_runtime.h>
#include <math.h>

#define NC 722
#define NF2 361            // float2 per row (722/2); rows 8B-aligned
#define NROWS 65536
#define ROWS_PER_WAVE 4
#define WAVES_PER_BLOCK 4
#define ROWS_PER_BLOCK 16
#define KITERS 6           // ceil(361/64)
#define NBLOCKS (NROWS / ROWS_PER_BLOCK)   // 4096

__global__ __launch_bounds__(256) void ce_gauss_kernel(
        const float* __restrict__ pred,
        const int* __restrict__ target,
        float* __restrict__ partials) {
    const int lane = threadIdx.x & 63;
    const int wave = threadIdx.x >> 6;
    __shared__ float wave_sums[WAVES_PER_BLOCK];

    const int row0 = blockIdx.x * ROWS_PER_BLOCK + wave * ROWS_PER_WAVE;

    // ---- phase 1: issue ALL 24 row loads unconditionally (clamped tail) ----
    const float2* __restrict__ p2[ROWS_PER_WAVE];
    #pragma unroll
    for (int rr = 0; rr < ROWS_PER_WAVE; ++rr)
        p2[rr] = (const float2*)(pred + (size_t)(row0 + rr) * NC);

    float2 v[ROWS_PER_WAVE][KITERS];
    #pragma unroll
    for (int k = 0; k < KITERS; ++k) {
        int idx = lane + (k << 6);
        if (idx > NF2 - 1) idx = NF2 - 1;   // clamp; only k=5, lane>40
        #pragma unroll
        for (int rr = 0; rr < ROWS_PER_WAVE; ++rr)
            v[rr][k] = p2[rr][idx];
    }

    // targets (wave-uniform values; kept in scalar/vector regs, NO arrays
    // with dynamic indices anywhere in this kernel -> no scratch)
    int t0 = target[row0 + 0];
    int t1 = target[row0 + 1];
    int t2 = target[row0 + 2];
    int t3 = target[row0 + 3];

    // ---- phase 2: exp + accumulate (tail lanes masked) ----
    float se[ROWS_PER_WAVE] = {0.f, 0.f, 0.f, 0.f};
    #pragma unroll
    for (int k = 0; k < KITERS; ++k) {
        const bool valid = (k < KITERS - 1) || (lane < NF2 - 5 * 64); // lane<41
        #pragma unroll
        for (int rr = 0; rr < ROWS_PER_WAVE; ++rr) {
            const float s = __expf(v[rr][k].x) + __expf(v[rr][k].y);
            se[rr] += valid ? s : 0.f;
        }
    }

    // ---- butterfly-reduce each row's sum-of-exp across the wave ----
    #pragma unroll
    for (int rr = 0; rr < ROWS_PER_WAVE; ++rr) {
        #pragma unroll
        for (int off = 32; off > 0; off >>= 1)
            se[rr] += __shfl_xor(se[rr], off, 64);
    }

    // ---- tap phase: lane = 8*grr + gj handles row grr, tap gj ----
    // Closed-form smoothed label: w(c) = DECAYS[|c-t|] for |c-t|<=3 and
    // 0<=c<NC, center = 1.0. (The reference's overwrite-scatter reduces to
    // this: the last writer at any slot, incl. clamped ones, is always the
    // smallest-dist writer.)
    const int grr = lane >> 3;   // 0..7 (rows 0..3 live; 4..7 masked)
    const int gj  = lane & 7;    // taps 0..6 live; 7 masked
    // select se / t for this lane's row without dynamic indexing
    const float se_sel = (grr & 2) ? ((grr & 1) ? se[3] : se[2])
                                   : ((grr & 1) ? se[1] : se[0]);
    const int   t_sel  = (grr & 2) ? ((grr & 1) ? t3 : t2)
                                   : ((grr & 1) ? t1 : t0);
    int ad = gj - 3; ad = (ad < 0) ? -ad : ad;      // |gj-3|, 0..4
    const float w = (ad == 0) ? 1.0f
                  : (ad == 1) ? 0.606530659713f     // exp(-1/2)
                  : (ad == 2) ? 0.367879441171f     // exp(-1)
                  : (ad == 3) ? 0.135335283237f     // exp(-2)
                  : 0.0f;                           // gj==7 slot
    const int c = t_sel - 3 + gj;
    const bool tap_valid = (grr < ROWS_PER_WAVE) & (gj < 7) &
                           (c >= 0) & (c <= NC - 1);
    int cc = c; if (cc < 0) cc = 0; if (cc > NC - 1) cc = NC - 1;
    const float pv = pred[(size_t)(row0 + (grr & 3)) * NC + cc];  // L1-hot
    const float lse = __logf(se_sel);
    float contrib = tap_valid ? (w * (lse - pv)) : 0.f;

    // reduce contributions of all rows/taps across the wave at once
    #pragma unroll
    for (int off = 32; off > 0; off >>= 1)
        contrib += __shfl_xor(contrib, off, 64);

    if (lane == 0) wave_sums[wave] = contrib;
    __syncthreads();
    if (threadIdx.x == 0) {
        partials[blockIdx.x] =
            wave_sums[0] + wave_sums[1] + wave_sums[2] + wave_sums[3];
    }
}

__global__ __launch_bounds__(256) void reduce_partials_kernel(
        const float* __restrict__ partials, float* __restrict__ out) {
    const int lane = threadIdx.x & 63;
    const int wave = threadIdx.x >> 6;
    __shared__ float ws[4];

    float s = 0.f;
    #pragma unroll
    for (int k = 0; k < NBLOCKS / 256; ++k)          // 16 coalesced iters
        s += partials[threadIdx.x + (k << 8)];
    #pragma unroll
    for (int off = 32; off > 0; off >>= 1)
        s += __shfl_xor(s, off, 64);
    if (lane == 0) ws[wave] = s;
    __syncthreads();
    if (threadIdx.x == 0)
        out[0] = (ws[0] + ws[1] + ws[2] + ws[3]) * (1.0f / (float)NROWS);
}

extern "C" void kernel_launch(void* const* d_in, const int* in_sizes, int n_in,
                              void* d_out, int out_size, void* d_ws, size_t ws_size,
                              hipStream_t stream) {
    const float* pred = (const float*)d_in[0];
    const int* target = (const int*)d_in[1];
    float* out = (float*)d_out;
    float* partials = (float*)d_ws;   // 4096 floats = 16 KB

    ce_gauss_kernel<<<NBLOCKS, 256, 0, stream>>>(pred, target, partials);
    reduce_partials_kernel<<<1, 256, 0, stream>>>(partials, out);
}